// Round 1
// baseline (2986.295 us; speedup 1.0000x reference)
//
#include <hip/hip_runtime.h>
#include <math.h>

// ---------------------------------------------------------------------------
// Sizes (fixed by the reference)
// V = 4096, READ_F = 24, INFO_F = 10, REF_LEN = 25, CONV_C = 32, KERN = 3
// READ_E = 128, INFO_E = 64, SEQ_E = 64, EMB = 256, FFN = 512, BLOCKS = 2
// ---------------------------------------------------------------------------

// ---------------- scan of counts -> exclusive offsets ----------------------
__global__ __launch_bounds__(256) void scan_counts(const int* __restrict__ cnt,
                                                   int* __restrict__ off, int V) {
    __shared__ int part[256];
    int t = threadIdx.x;
    int items = (V + 255) >> 8;
    int base = t * items;
    int s = 0;
    for (int i = 0; i < items; i++) {
        int idx = base + i;
        if (idx < V) s += cnt[idx];
    }
    part[t] = s;
    __syncthreads();
    for (int d = 1; d < 256; d <<= 1) {
        int v = (t >= d) ? part[t - d] : 0;
        __syncthreads();
        part[t] += v;
        __syncthreads();
    }
    int run = (t == 0) ? 0 : part[t - 1];
    for (int i = 0; i < items; i++) {
        int idx = base + i;
        if (idx < V) {
            off[idx] = run;
            run += cnt[idx];
        }
    }
    if (t == 255) off[V] = part[255];
}

// ---------------- fill per-read variant ids --------------------------------
__global__ void fill_ids(const int* __restrict__ off_r, int* __restrict__ rid_r,
                         const int* __restrict__ off_a, int* __restrict__ rid_a, int V) {
    int v = blockIdx.x * blockDim.x + threadIdx.x;
    if (v < V) {
        int s = off_r[v], e = off_r[v + 1];
        for (int r = s; r < e; r++) rid_r[r] = v;
    } else if (v < 2 * V) {
        int u = v - V;
        int s = off_a[u], e = off_a[u + 1];
        for (int r = s; r < e; r++) rid_a[r] = u;
    }
}

// ---------------- per-read MLP 24->128 relu ->128, write x[:,0:128] --------
__global__ __launch_bounds__(128) void read_mlp(
        const float* __restrict__ reads,
        const float* __restrict__ w1, const float* __restrict__ b1,
        const float* __restrict__ w2, const float* __restrict__ b2,
        float* __restrict__ xref, float* __restrict__ xalt, int R, int TR) {
    __shared__ float w1s[24 * 128];
    __shared__ float w2s[128 * 128];
    __shared__ float b1s[128], b2s[128];
    __shared__ float xs[4][24];
    __shared__ float hs[4][128];
    int t = threadIdx.x;
    for (int i = t; i < 24 * 128; i += 128) w1s[i] = w1[i];
    for (int i = t; i < 128 * 128; i += 128) w2s[i] = w2[i];
    b1s[t] = b1[t];
    b2s[t] = b2[t];
    __syncthreads();
    for (int base = blockIdx.x * 4; base < R; base += gridDim.x * 4) {
        int nr = min(4, R - base);
        for (int i = t; i < nr * 24; i += 128) xs[i / 24][i % 24] = reads[(size_t)base * 24 + i];
        __syncthreads();
        float h[4];
#pragma unroll
        for (int row = 0; row < 4; row++) h[row] = b1s[t];
#pragma unroll 4
        for (int k = 0; k < 24; k++) {
            float w = w1s[k * 128 + t];
#pragma unroll
            for (int row = 0; row < 4; row++) h[row] += xs[row][k] * w;
        }
#pragma unroll
        for (int row = 0; row < 4; row++) hs[row][t] = fmaxf(h[row], 0.f);
        __syncthreads();
        float o[4];
#pragma unroll
        for (int row = 0; row < 4; row++) o[row] = b2s[t];
#pragma unroll 4
        for (int k = 0; k < 128; k++) {
            float w = w2s[k * 128 + t];
#pragma unroll
            for (int row = 0; row < 4; row++) o[row] += hs[row][k] * w;
        }
        for (int row = 0; row < nr; row++) {
            int r = base + row;
            float* dst = (r < TR) ? (xref + (size_t)r * 256)
                                  : (xalt + (size_t)(r - TR) * 256);
            dst[t] = o[row];
        }
        __syncthreads();
    }
}

// ---------------- per-variant info MLP + conv + seq linear -> isv[V][128] --
__global__ __launch_bounds__(128) void variant_embed(
        const float* __restrict__ info2d, const float* __restrict__ oh,
        const float* __restrict__ iw1, const float* __restrict__ ib1,
        const float* __restrict__ iw2, const float* __restrict__ ib2,
        const float* __restrict__ cw, const float* __restrict__ cb,
        const float* __restrict__ sw, const float* __restrict__ sb,
        float* __restrict__ isv, int V) {
    __shared__ float iw1s[10 * 64], iw2s[64 * 64], ib1s[64], ib2s[64];
    __shared__ float cws[32 * 4 * 3], cbs[32];
    __shared__ float ohs[100], cv[736], his[64], infs[10];
    int v = blockIdx.x;
    int t = threadIdx.x;
    for (int i = t; i < 640; i += 128) iw1s[i] = iw1[i];
    for (int i = t; i < 4096; i += 128) iw2s[i] = iw2[i];
    for (int i = t; i < 384; i += 128) cws[i] = cw[i];
    if (t < 64) { ib1s[t] = ib1[t]; ib2s[t] = ib2[t]; }
    if (t < 32) cbs[t] = cb[t];
    for (int i = t; i < 100; i += 128) ohs[i] = oh[(size_t)v * 100 + i];
    if (t < 10) infs[t] = info2d[(size_t)v * 10 + t];
    __syncthreads();
    // conv -> relu, flattened [32*23]
    for (int j = t; j < 736; j += 128) {
        int c = j / 23, p = j - c * 23;
        float a = cbs[c];
#pragma unroll
        for (int i = 0; i < 4; i++)
#pragma unroll
            for (int k = 0; k < 3; k++)
                a += cws[(c * 4 + i) * 3 + k] * ohs[i * 25 + p + k];
        cv[j] = fmaxf(a, 0.f);
    }
    // info layer1
    if (t < 64) {
        float h = ib1s[t];
#pragma unroll
        for (int k = 0; k < 10; k++) h += infs[k] * iw1s[k * 64 + t];
        his[t] = fmaxf(h, 0.f);
    }
    __syncthreads();
    if (t < 64) {
        float o = ib2s[t];
        for (int k = 0; k < 64; k++) o += his[k] * iw2s[k * 64 + t];
        isv[(size_t)v * 128 + t] = o;
    } else {
        int tt = t - 64;
        float s = sb[tt];
        for (int j = 0; j < 736; j++) s += cv[j] * sw[j * 64 + tt];
        isv[(size_t)v * 128 + 64 + tt] = s;
    }
}

// ---------------- gather isv rows into x[:,128:256] ------------------------
__global__ void gather_isv(const float4* __restrict__ isv4,
                           const int* __restrict__ rid_r, const int* __restrict__ rid_a,
                           float4* __restrict__ xref4, float4* __restrict__ xalt4,
                           int TR, int TA) {
    long idx = (long)blockIdx.x * blockDim.x + threadIdx.x;
    long total = (long)(TR + TA) * 32;
    if (idx >= total) return;
    int r = (int)(idx >> 5);
    int q = (int)(idx & 31);
    if (r < TR)
        xref4[(size_t)r * 64 + 32 + q] = isv4[(size_t)rid_r[r] * 32 + q];
    else {
        int r2 = r - TR;
        xalt4[(size_t)r2 * 64 + 32 + q] = isv4[(size_t)rid_a[r2] * 32 + q];
    }
}

// ---------------- segment mean over rows of x ------------------------------
__global__ __launch_bounds__(256) void seg_mean(
        const float* __restrict__ xref, const int* __restrict__ off_r,
        const float* __restrict__ xalt, const int* __restrict__ off_a,
        float* __restrict__ mref, float* __restrict__ malt, int V) {
    int b = blockIdx.x;
    int t = threadIdx.x;
    const float* x;
    const int* off;
    float* out;
    int v;
    if (b < V) { x = xref; off = off_r; out = mref; v = b; }
    else { x = xalt; off = off_a; out = malt; v = b - V; }
    int s = off[v], e = off[v + 1];
    float acc = 0.f;
    for (int r = s; r < e; r++) acc += x[(size_t)r * 256 + t];
    out[(size_t)v * 256 + t] = acc / (float)(e - s);
}

// ---------------- generic tiled fp32 GEMM: C = epilogue(A@B + bias) --------
// MODE: 0 none, 1 relu, 2 sigmoid, 3 relu*gate[rid[row]], 4 C += (residual)
template <int MODE>
__global__ __launch_bounds__(256) void gemm_full(
        const float* __restrict__ A, const float* __restrict__ B,
        const float* __restrict__ bias, float* __restrict__ C,
        int M, int N, int K,
        const int* __restrict__ rid, const float* __restrict__ gate) {
    __shared__ float As[16][68];
    __shared__ float Bs[16][68];
    int m0 = blockIdx.x * 64, n0 = blockIdx.y * 64;
    int t = threadIdx.x;
    int ar = t >> 2, ak = (t & 3) * 4;
    int bk = t >> 4, bc = (t & 15) * 4;
    int tm = (t >> 4) * 4, tn = (t & 15) * 4;
    float acc[4][4] = {};
    for (int kt = 0; kt < K; kt += 16) {
        float4 av4;
        int arow = m0 + ar;
        if (arow < M)
            av4 = *(const float4*)&A[(size_t)arow * K + kt + ak];
        else
            av4 = make_float4(0.f, 0.f, 0.f, 0.f);
        As[ak + 0][ar] = av4.x;
        As[ak + 1][ar] = av4.y;
        As[ak + 2][ar] = av4.z;
        As[ak + 3][ar] = av4.w;
        float4 bv4 = *(const float4*)&B[(size_t)(kt + bk) * N + n0 + bc];
        *(float4*)&Bs[bk][bc] = bv4;
        __syncthreads();
#pragma unroll
        for (int k = 0; k < 16; k++) {
            const float4 a = *(const float4*)&As[k][tm];
            const float4 b = *(const float4*)&Bs[k][tn];
            const float aa[4] = {a.x, a.y, a.z, a.w};
            const float bb[4] = {b.x, b.y, b.z, b.w};
#pragma unroll
            for (int i = 0; i < 4; i++)
#pragma unroll
                for (int j = 0; j < 4; j++) acc[i][j] += aa[i] * bb[j];
        }
        __syncthreads();
    }
    float bb4[4] = {bias[n0 + tn], bias[n0 + tn + 1], bias[n0 + tn + 2], bias[n0 + tn + 3]};
#pragma unroll
    for (int i = 0; i < 4; i++) {
        int row = m0 + tm + i;
        if (row >= M) break;
        float v[4];
#pragma unroll
        for (int j = 0; j < 4; j++) v[j] = acc[i][j] + bb4[j];
        if (MODE == 1) {
#pragma unroll
            for (int j = 0; j < 4; j++) v[j] = fmaxf(v[j], 0.f);
        } else if (MODE == 2) {
#pragma unroll
            for (int j = 0; j < 4; j++) v[j] = 1.f / (1.f + expf(-v[j]));
        } else if (MODE == 3) {
            int vid = rid[row];
            const float* g = gate + (size_t)vid * N + n0 + tn;
#pragma unroll
            for (int j = 0; j < 4; j++) v[j] = fmaxf(v[j], 0.f) * g[j];
        }
        float* cp = C + (size_t)row * N + n0 + tn;
        if (MODE == 4) {
#pragma unroll
            for (int j = 0; j < 4; j++) cp[j] += v[j];
        } else {
#pragma unroll
            for (int j = 0; j < 4; j++) cp[j] = v[j];
        }
    }
}

// ---------------- weighted alt segment sums --------------------------------
__global__ void alt_wsum(const float* __restrict__ au, const int* __restrict__ off_a,
                         float* __restrict__ wsum, int V) {
    int v = blockIdx.x * blockDim.x + threadIdx.x;
    if (v >= V) return;
    float s = 0.f;
    for (int r = off_a[v]; r < off_a[v + 1]; r++) s += 1.2f - 0.4f * au[r];
    wsum[v] = s;
}

__global__ __launch_bounds__(256) void alt_weighted_mean(
        const float* __restrict__ xalt, const float* __restrict__ au,
        const int* __restrict__ off_a, const float* __restrict__ wsum,
        float* __restrict__ av, int V) {
    int v = blockIdx.x;
    int t = threadIdx.x;
    int s = off_a[v], e = off_a[v + 1];
    float inv = 1.f / wsum[v];
    float acc = 0.f;
    for (int r = s; r < e; r++) {
        float w = (1.2f - 0.4f * au[r]) * inv;
        acc += xalt[(size_t)r * 256 + t] * w;
    }
    av[(size_t)v * 256 + t] = acc;
}

// ---------------------------------------------------------------------------
extern "C" void kernel_launch(void* const* d_in, const int* in_sizes, int n_in,
                              void* d_out, int out_size, void* d_ws, size_t ws_size,
                              hipStream_t stream) {
    const float* reads = (const float*)d_in[0];
    const float* info2d = (const float*)d_in[1];
    const float* oh = (const float*)d_in[2];
    const float* au = (const float*)d_in[3];
    const int* ref_counts = (const int*)d_in[4];
    const int* alt_counts = (const int*)d_in[5];
    const float* rw1 = (const float*)d_in[6];
    const float* rb1 = (const float*)d_in[7];
    const float* rw2 = (const float*)d_in[8];
    const float* rb2 = (const float*)d_in[9];
    const float* iw1 = (const float*)d_in[10];
    const float* ib1 = (const float*)d_in[11];
    const float* iw2 = (const float*)d_in[12];
    const float* ib2 = (const float*)d_in[13];
    const float* cw = (const float*)d_in[14];
    const float* cb = (const float*)d_in[15];
    const float* sw = (const float*)d_in[16];
    const float* sb = (const float*)d_in[17];
    const float* blk_w1 = (const float*)d_in[18];
    const float* blk_b1 = (const float*)d_in[19];
    const float* blk_wg = (const float*)d_in[20];
    const float* blk_bg = (const float*)d_in[21];
    const float* blk_w2 = (const float*)d_in[22];
    const float* blk_b2 = (const float*)d_in[23];
    const float* agg_w1 = (const float*)d_in[24];
    const float* agg_b1 = (const float*)d_in[25];
    const float* agg_w2 = (const float*)d_in[26];
    const float* agg_b2 = (const float*)d_in[27];

    const int R = in_sizes[0] / 24;
    const int TA = in_sizes[3];
    const int TR = R - TA;
    const int V = in_sizes[4];

    // ---- workspace carve (256B aligned slices) ----
    size_t p = 0;
    auto carve = [&](size_t bytes) -> void* {
        void* q = (char*)d_ws + p;
        p = (p + bytes + 255) & ~(size_t)255;
        return q;
    };
    int* off_r = (int*)carve((V + 1) * sizeof(int));
    int* off_a = (int*)carve((V + 1) * sizeof(int));
    int* rid_r = (int*)carve((size_t)TR * sizeof(int));
    int* rid_a = (int*)carve((size_t)TA * sizeof(int));
    float* isv = (float*)carve((size_t)V * 128 * sizeof(float));
    float* xref = (float*)carve((size_t)TR * 256 * sizeof(float));
    float* xalt = (float*)carve((size_t)TA * 256 * sizeof(float));
    float* mref = (float*)carve((size_t)V * 256 * sizeof(float));
    float* malt = (float*)carve((size_t)V * 256 * sizeof(float));
    float* gate_r = (float*)carve((size_t)V * 512 * sizeof(float));
    float* gate_a = (float*)carve((size_t)V * 512 * sizeof(float));
    const int CHUNK = 16384;
    float* hbuf = (float*)carve((size_t)CHUNK * 512 * sizeof(float));
    float* wsum = (float*)carve((size_t)V * sizeof(float));
    float* avb = (float*)carve((size_t)V * 256 * sizeof(float));
    float* aggh = (float*)carve((size_t)V * 256 * sizeof(float));
    (void)ws_size;
    (void)n_in;
    (void)out_size;

    // ---- offsets / ids ----
    scan_counts<<<1, 256, 0, stream>>>(ref_counts, off_r, V);
    scan_counts<<<1, 256, 0, stream>>>(alt_counts, off_a, V);
    fill_ids<<<(2 * V + 255) / 256, 256, 0, stream>>>(off_r, rid_r, off_a, rid_a, V);

    // ---- embeddings ----
    read_mlp<<<2048, 128, 0, stream>>>(reads, rw1, rb1, rw2, rb2, xref, xalt, R, TR);
    variant_embed<<<V, 128, 0, stream>>>(info2d, oh, iw1, ib1, iw2, ib2, cw, cb, sw, sb, isv, V);
    long gtot = (long)R * 32;
    gather_isv<<<(int)((gtot + 255) / 256), 256, 0, stream>>>(
        (const float4*)isv, rid_r, rid_a, (float4*)xref, (float4*)xalt, TR, TA);

    // ---- 2 gated residual blocks ----
    for (int it = 0; it < 2; ++it) {
        const float* W1 = blk_w1 + (size_t)it * 256 * 512;
        const float* B1 = blk_b1 + (size_t)it * 512;
        const float* Wg = blk_wg + (size_t)it * 256 * 512;
        const float* Bg = blk_bg + (size_t)it * 512;
        const float* W2 = blk_w2 + (size_t)it * 512 * 256;
        const float* B2 = blk_b2 + (size_t)it * 256;

        seg_mean<<<2 * V, 256, 0, stream>>>(xref, off_r, xalt, off_a, mref, malt, V);

        dim3 gg((V + 63) / 64, 512 / 64);
        // gate for ref update: sigmoid(alt_mean @ Wg + bg)
        gemm_full<2><<<gg, 256, 0, stream>>>(malt, Wg, Bg, gate_r, V, 512, 256, nullptr, nullptr);
        // gate for alt update: sigmoid(ref_mean @ Wg + bg)
        gemm_full<2><<<gg, 256, 0, stream>>>(mref, Wg, Bg, gate_a, V, 512, 256, nullptr, nullptr);

        for (int c0 = 0; c0 < TR; c0 += CHUNK) {
            int cm = min(CHUNK, TR - c0);
            dim3 g1((cm + 63) / 64, 8);
            gemm_full<3><<<g1, 256, 0, stream>>>(xref + (size_t)c0 * 256, W1, B1, hbuf,
                                                 cm, 512, 256, rid_r + c0, gate_r);
            dim3 g2((cm + 63) / 64, 4);
            gemm_full<4><<<g2, 256, 0, stream>>>(hbuf, W2, B2, xref + (size_t)c0 * 256,
                                                 cm, 256, 512, nullptr, nullptr);
        }
        for (int c0 = 0; c0 < TA; c0 += CHUNK) {
            int cm = min(CHUNK, TA - c0);
            dim3 g1((cm + 63) / 64, 8);
            gemm_full<3><<<g1, 256, 0, stream>>>(xalt + (size_t)c0 * 256, W1, B1, hbuf,
                                                 cm, 512, 256, rid_a + c0, gate_a);
            dim3 g2((cm + 63) / 64, 4);
            gemm_full<4><<<g2, 256, 0, stream>>>(hbuf, W2, B2, xalt + (size_t)c0 * 256,
                                                 cm, 256, 512, nullptr, nullptr);
        }
    }

    // ---- weighted alt means + agg MLP ----
    alt_wsum<<<(V + 255) / 256, 256, 0, stream>>>(au, off_a, wsum, V);
    alt_weighted_mean<<<V, 256, 0, stream>>>(xalt, au, off_a, wsum, avb, V);

    dim3 ga((V + 63) / 64, 256 / 64);
    gemm_full<1><<<ga, 256, 0, stream>>>(avb, agg_w1, agg_b1, aggh, V, 256, 256, nullptr, nullptr);
    dim3 go((V + 63) / 64, 128 / 64);
    gemm_full<0><<<go, 256, 0, stream>>>(aggh, agg_w2, agg_b2, (float*)d_out, V, 128, 256, nullptr, nullptr);
}

// Round 2
// 921.249 us; speedup vs baseline: 3.2416x; 3.2416x over previous
//
#include <hip/hip_runtime.h>
#include <math.h>

// ---------------------------------------------------------------------------
// V=4096, READ_F=24, INFO_F=10, REF_LEN=25, CONV_C=32, KERN=3
// READ_E=128, INFO_E=64, SEQ_E=64, EMB=256, FFN=512, BLOCKS=2
// ---------------------------------------------------------------------------

typedef short short8 __attribute__((ext_vector_type(8)));
typedef __bf16 bf16x8 __attribute__((ext_vector_type(8)));
typedef float f32x4 __attribute__((ext_vector_type(4)));

__device__ inline unsigned short f2bf(float f) {
    unsigned u = __builtin_bit_cast(unsigned, f);
    u += 0x7fffu + ((u >> 16) & 1u);   // RNE
    return (unsigned short)(u >> 16);
}

__device__ inline f32x4 mfma16(short8 a, short8 b, f32x4 c) {
    return __builtin_amdgcn_mfma_f32_16x16x32_bf16(
        __builtin_bit_cast(bf16x8, a), __builtin_bit_cast(bf16x8, b), c, 0, 0, 0);
}

// XOR-swizzled LDS element index (16B-granule swizzle; T2 / G4 pattern)
__device__ inline int lds_idx(int row, int k, int Kp, int mask) {
    int b = (k << 1) ^ ((row & mask) << 4);
    return row * Kp + (b >> 1);
}

// ---------------- scan of counts -> exclusive offsets ----------------------
__global__ __launch_bounds__(256) void scan_counts(const int* __restrict__ cnt,
                                                   int* __restrict__ off, int V) {
    __shared__ int part[256];
    int t = threadIdx.x;
    int items = (V + 255) >> 8;
    int base = t * items;
    int s = 0;
    for (int i = 0; i < items; i++) {
        int idx = base + i;
        if (idx < V) s += cnt[idx];
    }
    part[t] = s;
    __syncthreads();
    for (int d = 1; d < 256; d <<= 1) {
        int v = (t >= d) ? part[t - d] : 0;
        __syncthreads();
        part[t] += v;
        __syncthreads();
    }
    int run = (t == 0) ? 0 : part[t - 1];
    for (int i = 0; i < items; i++) {
        int idx = base + i;
        if (idx < V) {
            off[idx] = run;
            run += cnt[idx];
        }
    }
    if (t == 255) off[V] = part[255];
}

__global__ void fill_ids(const int* __restrict__ off_r, int* __restrict__ rid_r,
                         const int* __restrict__ off_a, int* __restrict__ rid_a, int V) {
    int v = blockIdx.x * blockDim.x + threadIdx.x;
    if (v < V) {
        int s = off_r[v], e = off_r[v + 1];
        for (int r = s; r < e; r++) rid_r[r] = v;
    } else if (v < 2 * V) {
        int u = v - V;
        int s = off_a[u], e = off_a[u + 1];
        for (int r = s; r < e; r++) rid_a[r] = u;
    }
}

// ---------------- fp32 [K][N] -> bf16 [N][Kp] transpose (zero-padded K) ----
__global__ void transpose_bf16(const float* __restrict__ src, unsigned short* __restrict__ dst,
                               int K, int N, int Kp) {
    int idx = blockIdx.x * 256 + threadIdx.x;
    if (idx >= N * Kp) return;
    int n = idx / Kp, k = idx - n * Kp;
    dst[idx] = (k < K) ? f2bf(src[(size_t)k * N + n]) : (unsigned short)0;
}

// ---------------- reads fp32 [R][24] -> bf16 [R][32] (zero pad) ------------
__global__ void reads_to_bf(const float* __restrict__ reads, unsigned short* __restrict__ out,
                            int R) {
    int idx = blockIdx.x * 256 + threadIdx.x;
    if (idx >= R * 32) return;
    int r = idx >> 5, k = idx & 31;
    out[idx] = (k < 24) ? f2bf(reads[(size_t)r * 24 + k]) : (unsigned short)0;
}

// ---------------- generic MFMA GEMM: C = epi(A[M,K] @ Bt[N,K]^T + bias) ----
// EPI: 0 fp32 store, 1 relu->bf16 store, 2 sigmoid->fp32, 3 fp32 split ref/alt
template <int EPI>
__global__ __launch_bounds__(256, 4) void gemm_bf16(
        const unsigned short* __restrict__ A, const unsigned short* __restrict__ Bt,
        const float* __restrict__ bias, void* __restrict__ C0, void* __restrict__ C1,
        int M, int K, int mask, int ldc, int TR) {
    extern __shared__ unsigned short As[];
    const int m0 = blockIdx.x * 64, n0 = blockIdx.y * 64;
    const int tid = threadIdx.x;
    const int kc = K >> 3;
    for (int i = tid; i < (kc << 6); i += 256) {
        int r = i / kc, k8 = (i - r * kc) << 3;
        short8 v = {0, 0, 0, 0, 0, 0, 0, 0};
        if (m0 + r < M) v = *(const short8*)(A + (size_t)(m0 + r) * K + k8);
        *(short8*)&As[lds_idx(r, k8, K, mask)] = v;
    }
    __syncthreads();
    const int wid = tid >> 6, lane = tid & 63;
    const int lr = lane & 15, lg = lane >> 4;
    f32x4 acc[4];
#pragma unroll
    for (int ct = 0; ct < 4; ++ct) acc[ct] = f32x4{0.f, 0.f, 0.f, 0.f};
    const unsigned short* Bb = Bt + (size_t)(n0 + lr) * K + (lg << 3);
    const int nk = K >> 5;
    for (int s = 0; s < nk; ++s) {
        int k0 = (s << 5) + (lg << 3);
        short8 af = *(const short8*)&As[lds_idx((wid << 4) + lr, k0, K, mask)];
#pragma unroll
        for (int ct = 0; ct < 4; ++ct) {
            short8 bf = *(const short8*)(Bb + (size_t)(ct << 4) * K + (s << 5));
            acc[ct] = mfma16(af, bf, acc[ct]);
        }
    }
#pragma unroll
    for (int ct = 0; ct < 4; ++ct) {
        int c = n0 + (ct << 4) + lr;
        float bb = bias[c];
#pragma unroll
        for (int q = 0; q < 4; ++q) {
            int rg = m0 + (wid << 4) + (lg << 2) + q;
            if (rg >= M) continue;
            float v = acc[ct][q] + bb;
            if (EPI == 0) {
                ((float*)C0)[(size_t)rg * ldc + c] = v;
            } else if (EPI == 1) {
                ((unsigned short*)C0)[(size_t)rg * ldc + c] = f2bf(fmaxf(v, 0.f));
            } else if (EPI == 2) {
                ((float*)C0)[(size_t)rg * ldc + c] = 1.f / (1.f + __expf(-v));
            } else {
                float* base = (rg < TR) ? ((float*)C0 + (size_t)rg * ldc)
                                        : ((float*)C1 + (size_t)(rg - TR) * ldc);
                base[c] = v;
            }
        }
    }
}

// ---------------- per-variant info MLP + conv + seq linear -> isv[V][128] --
__global__ __launch_bounds__(128) void variant_embed(
        const float* __restrict__ info2d, const float* __restrict__ oh,
        const float* __restrict__ iw1, const float* __restrict__ ib1,
        const float* __restrict__ iw2, const float* __restrict__ ib2,
        const float* __restrict__ cw, const float* __restrict__ cb,
        const float* __restrict__ sw, const float* __restrict__ sb,
        float* __restrict__ isv, int V) {
    __shared__ float iw1s[10 * 64], iw2s[64 * 64], ib1s[64], ib2s[64];
    __shared__ float cws[32 * 4 * 3], cbs[32];
    __shared__ float ohs[100], cv[736], his[64], infs[10];
    int v = blockIdx.x;
    int t = threadIdx.x;
    for (int i = t; i < 640; i += 128) iw1s[i] = iw1[i];
    for (int i = t; i < 4096; i += 128) iw2s[i] = iw2[i];
    for (int i = t; i < 384; i += 128) cws[i] = cw[i];
    if (t < 64) { ib1s[t] = ib1[t]; ib2s[t] = ib2[t]; }
    if (t < 32) cbs[t] = cb[t];
    for (int i = t; i < 100; i += 128) ohs[i] = oh[(size_t)v * 100 + i];
    if (t < 10) infs[t] = info2d[(size_t)v * 10 + t];
    __syncthreads();
    for (int j = t; j < 736; j += 128) {
        int c = j / 23, p = j - c * 23;
        float a = cbs[c];
#pragma unroll
        for (int i = 0; i < 4; i++)
#pragma unroll
            for (int k = 0; k < 3; k++)
                a += cws[(c * 4 + i) * 3 + k] * ohs[i * 25 + p + k];
        cv[j] = fmaxf(a, 0.f);
    }
    if (t < 64) {
        float h = ib1s[t];
#pragma unroll
        for (int k = 0; k < 10; k++) h += infs[k] * iw1s[k * 64 + t];
        his[t] = fmaxf(h, 0.f);
    }
    __syncthreads();
    if (t < 64) {
        float o = ib2s[t];
        for (int k = 0; k < 64; k++) o += his[k] * iw2s[k * 64 + t];
        isv[(size_t)v * 128 + t] = o;
    } else {
        int tt = t - 64;
        float s = sb[tt];
        for (int j = 0; j < 736; j++) s += cv[j] * sw[j * 64 + tt];
        isv[(size_t)v * 128 + 64 + tt] = s;
    }
}

// ---------------- gather isv rows into x[:,128:256] ------------------------
__global__ void gather_isv(const float4* __restrict__ isv4,
                           const int* __restrict__ rid_r, const int* __restrict__ rid_a,
                           float4* __restrict__ xref4, float4* __restrict__ xalt4,
                           int TR, int TA) {
    long idx = (long)blockIdx.x * blockDim.x + threadIdx.x;
    long total = (long)(TR + TA) * 32;
    if (idx >= total) return;
    int r = (int)(idx >> 5);
    int q = (int)(idx & 31);
    if (r < TR)
        xref4[(size_t)r * 64 + 32 + q] = isv4[(size_t)rid_r[r] * 32 + q];
    else {
        int r2 = r - TR;
        xalt4[(size_t)r2 * 64 + 32 + q] = isv4[(size_t)rid_a[r2] * 32 + q];
    }
}

// ---------------- segment mean over rows of x -> bf16 ----------------------
__global__ __launch_bounds__(256) void seg_mean_bf(
        const float* __restrict__ xref, const int* __restrict__ off_r,
        const float* __restrict__ xalt, const int* __restrict__ off_a,
        unsigned short* __restrict__ mref, unsigned short* __restrict__ malt, int V) {
    int b = blockIdx.x;
    int t = threadIdx.x;
    const float* x;
    const int* off;
    unsigned short* out;
    int v;
    if (b < V) { x = xref; off = off_r; out = mref; v = b; }
    else { x = xalt; off = off_a; out = malt; v = b - V; }
    int s = off[v], e = off[v + 1];
    float acc = 0.f;
    for (int r = s; r < e; r++) acc += x[(size_t)r * 256 + t];
    out[(size_t)v * 256 + t] = f2bf(acc / (float)(e - s));
}

// ---------------- fused gated residual block -------------------------------
// One 64-row tile per 512-thread (8-wave) workgroup:
//   Xs(bf16,swz) <- x ; H = relu(Xs@W1t^T+b1)*gate[rid] -> Hs(bf16,swz)
//   x += Hs@W2t^T + b2      (all epilogue math fp32)
__global__ __launch_bounds__(512, 2) void fused_block(
        float* __restrict__ xref, float* __restrict__ xalt,
        const unsigned short* __restrict__ W1t,   // [512][256]
        const unsigned short* __restrict__ W2t,   // [256][512]
        const float* __restrict__ b1, const float* __restrict__ b2,
        const float* __restrict__ gate_r, const float* __restrict__ gate_a,
        const int* __restrict__ rid_r, const int* __restrict__ rid_a,
        int TR, int TA, int ntr) {
    __shared__ unsigned short Xs[64 * 256];
    __shared__ unsigned short Hs[64 * 512];
    __shared__ int rid_s[64];
    const int bid = blockIdx.x;
    const bool isref = bid < ntr;
    const int m0 = (isref ? bid : bid - ntr) * 64;
    const int M = isref ? TR : TA;
    float* x = isref ? xref : xalt;
    const float* gate = isref ? gate_r : gate_a;
    const int* rid = isref ? rid_r : rid_a;
    const int tid = threadIdx.x;
    if (tid < 64) rid_s[tid] = (m0 + tid < M) ? rid[m0 + tid] : 0;
    // stage X fp32 -> bf16 swizzled
    for (int i = tid; i < 64 * 32; i += 512) {
        int r = i >> 5, k8 = (i & 31) << 3;
        short8 v = {0, 0, 0, 0, 0, 0, 0, 0};
        if (m0 + r < M) {
            const float* s = x + (size_t)(m0 + r) * 256 + k8;
            float4 a = *(const float4*)s;
            float4 bq = *(const float4*)(s + 4);
            v[0] = (short)f2bf(a.x); v[1] = (short)f2bf(a.y);
            v[2] = (short)f2bf(a.z); v[3] = (short)f2bf(a.w);
            v[4] = (short)f2bf(bq.x); v[5] = (short)f2bf(bq.y);
            v[6] = (short)f2bf(bq.z); v[7] = (short)f2bf(bq.w);
        }
        *(short8*)&Xs[lds_idx(r, k8, 256, 7)] = v;
    }
    __syncthreads();
    const int wid = tid >> 6, lane = tid & 63;
    const int lr = lane & 15, lg = lane >> 4;
    // ---- GEMM1: 64 x 512, each wave 64 cols, K=256 (8 steps) ----
    f32x4 acc1[4][4];
#pragma unroll
    for (int i = 0; i < 4; ++i)
#pragma unroll
        for (int j = 0; j < 4; ++j) acc1[i][j] = f32x4{0.f, 0.f, 0.f, 0.f};
    const int n1 = wid * 64;
    const unsigned short* Bb1 = W1t + (size_t)(n1 + lr) * 256 + (lg << 3);
    short8 bcur[4], bnxt[4];
#pragma unroll
    for (int ct = 0; ct < 4; ++ct) bcur[ct] = *(const short8*)(Bb1 + ct * 4096);
#pragma unroll
    for (int s = 0; s < 8; ++s) {
        if (s < 7) {
#pragma unroll
            for (int ct = 0; ct < 4; ++ct)
                bnxt[ct] = *(const short8*)(Bb1 + ct * 4096 + (s + 1) * 32);
        }
        int k0 = (s << 5) + (lg << 3);
        short8 af[4];
#pragma unroll
        for (int rt = 0; rt < 4; ++rt)
            af[rt] = *(const short8*)&Xs[lds_idx(rt * 16 + lr, k0, 256, 7)];
#pragma unroll
        for (int rt = 0; rt < 4; ++rt)
#pragma unroll
            for (int ct = 0; ct < 4; ++ct)
                acc1[rt][ct] = mfma16(af[rt], bcur[ct], acc1[rt][ct]);
#pragma unroll
        for (int ct = 0; ct < 4; ++ct) bcur[ct] = bnxt[ct];
    }
    // epilogue 1: relu * gate -> Hs (bf16, swizzled)
    float bb1[4];
#pragma unroll
    for (int ct = 0; ct < 4; ++ct) bb1[ct] = b1[n1 + ct * 16 + lr];
#pragma unroll
    for (int rt = 0; rt < 4; ++rt)
#pragma unroll
        for (int ct = 0; ct < 4; ++ct) {
            int n = n1 + ct * 16 + lr;
#pragma unroll
            for (int q = 0; q < 4; ++q) {
                int rl = rt * 16 + (lg << 2) + q;
                float h = acc1[rt][ct][q] + bb1[ct];
                h = fmaxf(h, 0.f) * gate[(size_t)rid_s[rl] * 512 + n];
                Hs[lds_idx(rl, n, 512, 7)] = f2bf(h);
            }
        }
    __syncthreads();
    // ---- GEMM2: 64 x 256, each wave 32 cols, K=512 (16 steps) ----
    f32x4 acc2[4][2];
#pragma unroll
    for (int i = 0; i < 4; ++i)
#pragma unroll
        for (int j = 0; j < 2; ++j) acc2[i][j] = f32x4{0.f, 0.f, 0.f, 0.f};
    const int n2 = wid * 32;
    const unsigned short* Bb2 = W2t + (size_t)(n2 + lr) * 512 + (lg << 3);
    short8 ccur[2], cnxt[2];
#pragma unroll
    for (int ct = 0; ct < 2; ++ct) ccur[ct] = *(const short8*)(Bb2 + ct * 8192);
#pragma unroll
    for (int s = 0; s < 16; ++s) {
        if (s < 15) {
#pragma unroll
            for (int ct = 0; ct < 2; ++ct)
                cnxt[ct] = *(const short8*)(Bb2 + ct * 8192 + (s + 1) * 32);
        }
        int k0 = (s << 5) + (lg << 3);
        short8 af[4];
#pragma unroll
        for (int rt = 0; rt < 4; ++rt)
            af[rt] = *(const short8*)&Hs[lds_idx(rt * 16 + lr, k0, 512, 7)];
#pragma unroll
        for (int rt = 0; rt < 4; ++rt)
#pragma unroll
            for (int ct = 0; ct < 2; ++ct)
                acc2[rt][ct] = mfma16(af[rt], ccur[ct], acc2[rt][ct]);
#pragma unroll
        for (int ct = 0; ct < 2; ++ct) ccur[ct] = cnxt[ct];
    }
    // epilogue 2: residual add in fp32
#pragma unroll
    for (int ct = 0; ct < 2; ++ct) {
        int c = n2 + (ct << 4) + lr;
        float bb = b2[c];
#pragma unroll
        for (int rt = 0; rt < 4; ++rt)
#pragma unroll
            for (int q = 0; q < 4; ++q) {
                int rl = rt * 16 + (lg << 2) + q;
                int rg = m0 + rl;
                if (rg < M) {
                    float* pdst = x + (size_t)rg * 256 + c;
                    *pdst += acc2[rt][ct][q] + bb;
                }
            }
    }
}

// ---------------- weighted alt segment sums --------------------------------
__global__ void alt_wsum(const float* __restrict__ au, const int* __restrict__ off_a,
                         float* __restrict__ wsum, int V) {
    int v = blockIdx.x * blockDim.x + threadIdx.x;
    if (v >= V) return;
    float s = 0.f;
    for (int r = off_a[v]; r < off_a[v + 1]; r++) s += 1.2f - 0.4f * au[r];
    wsum[v] = s;
}

__global__ __launch_bounds__(256) void alt_weighted_mean_bf(
        const float* __restrict__ xalt, const float* __restrict__ au,
        const int* __restrict__ off_a, const float* __restrict__ wsum,
        unsigned short* __restrict__ av, int V) {
    int v = blockIdx.x;
    int t = threadIdx.x;
    int s = off_a[v], e = off_a[v + 1];
    float inv = 1.f / wsum[v];
    float acc = 0.f;
    for (int r = s; r < e; r++) {
        float w = (1.2f - 0.4f * au[r]) * inv;
        acc += xalt[(size_t)r * 256 + t] * w;
    }
    av[(size_t)v * 256 + t] = f2bf(acc);
}

// ---------------------------------------------------------------------------
extern "C" void kernel_launch(void* const* d_in, const int* in_sizes, int n_in,
                              void* d_out, int out_size, void* d_ws, size_t ws_size,
                              hipStream_t stream) {
    const float* reads = (const float*)d_in[0];
    const float* info2d = (const float*)d_in[1];
    const float* oh = (const float*)d_in[2];
    const float* au = (const float*)d_in[3];
    const int* ref_counts = (const int*)d_in[4];
    const int* alt_counts = (const int*)d_in[5];
    const float* rw1 = (const float*)d_in[6];
    const float* rb1 = (const float*)d_in[7];
    const float* rw2 = (const float*)d_in[8];
    const float* rb2 = (const float*)d_in[9];
    const float* iw1 = (const float*)d_in[10];
    const float* ib1 = (const float*)d_in[11];
    const float* iw2 = (const float*)d_in[12];
    const float* ib2 = (const float*)d_in[13];
    const float* cw = (const float*)d_in[14];
    const float* cb = (const float*)d_in[15];
    const float* sw = (const float*)d_in[16];
    const float* sb = (const float*)d_in[17];
    const float* blk_w1 = (const float*)d_in[18];
    const float* blk_b1 = (const float*)d_in[19];
    const float* blk_wg = (const float*)d_in[20];
    const float* blk_bg = (const float*)d_in[21];
    const float* blk_w2 = (const float*)d_in[22];
    const float* blk_b2 = (const float*)d_in[23];
    const float* agg_w1 = (const float*)d_in[24];
    const float* agg_b1 = (const float*)d_in[25];
    const float* agg_w2 = (const float*)d_in[26];
    const float* agg_b2 = (const float*)d_in[27];

    const int R = in_sizes[0] / 24;
    const int TA = in_sizes[3];
    const int TR = R - TA;
    const int V = in_sizes[4];

    size_t p = 0;
    auto carve = [&](size_t bytes) -> void* {
        void* q = (char*)d_ws + p;
        p = (p + bytes + 255) & ~(size_t)255;
        return q;
    };
    // persistent region
    int* off_r = (int*)carve((V + 1) * sizeof(int));
    int* off_a = (int*)carve((V + 1) * sizeof(int));
    int* rid_r = (int*)carve((size_t)TR * sizeof(int));
    int* rid_a = (int*)carve((size_t)TA * sizeof(int));
    float* isv = (float*)carve((size_t)V * 128 * sizeof(float));
    float* xref = (float*)carve((size_t)TR * 256 * sizeof(float));
    float* xalt = (float*)carve((size_t)TA * 256 * sizeof(float));
    unsigned short* W1t0 = (unsigned short*)carve((size_t)512 * 256 * 2);
    unsigned short* W1t1 = (unsigned short*)carve((size_t)512 * 256 * 2);
    unsigned short* Wgt0 = (unsigned short*)carve((size_t)512 * 256 * 2);
    unsigned short* Wgt1 = (unsigned short*)carve((size_t)512 * 256 * 2);
    unsigned short* W2t0 = (unsigned short*)carve((size_t)256 * 512 * 2);
    unsigned short* W2t1 = (unsigned short*)carve((size_t)256 * 512 * 2);
    unsigned short* RW1t = (unsigned short*)carve((size_t)128 * 32 * 2);
    unsigned short* RW2t = (unsigned short*)carve((size_t)128 * 128 * 2);
    unsigned short* AG1t = (unsigned short*)carve((size_t)256 * 256 * 2);
    unsigned short* AG2t = (unsigned short*)carve((size_t)128 * 256 * 2);
    float* wsum = (float*)carve((size_t)V * sizeof(float));
    // union region A: read-MLP temporaries (dead after layer2)
    size_t mark = p;
    unsigned short* reads_bf = (unsigned short*)carve((size_t)R * 32 * 2);
    unsigned short* h1 = (unsigned short*)carve((size_t)R * 128 * 2);
    size_t endA = p;
    // union region B: block-loop + aggregation buffers (live after layer2)
    p = mark;
    unsigned short* mref_bf = (unsigned short*)carve((size_t)V * 256 * 2);
    unsigned short* malt_bf = (unsigned short*)carve((size_t)V * 256 * 2);
    float* gate_r = (float*)carve((size_t)V * 512 * sizeof(float));
    float* gate_a = (float*)carve((size_t)V * 512 * sizeof(float));
    unsigned short* avb_bf = (unsigned short*)carve((size_t)V * 256 * 2);
    unsigned short* aggh_bf = (unsigned short*)carve((size_t)V * 256 * 2);
    if (endA > p) p = endA;
    (void)ws_size; (void)n_in; (void)out_size;

    // ---- offsets / ids ----
    scan_counts<<<1, 256, 0, stream>>>(ref_counts, off_r, V);
    scan_counts<<<1, 256, 0, stream>>>(alt_counts, off_a, V);
    fill_ids<<<(2 * V + 255) / 256, 256, 0, stream>>>(off_r, rid_r, off_a, rid_a, V);

    // ---- weight transposes (fp32 -> bf16 [N][Kp]) ----
    auto T = [&](const float* src, unsigned short* dst, int K, int N, int Kp) {
        int tot = N * Kp;
        transpose_bf16<<<(tot + 255) / 256, 256, 0, stream>>>(src, dst, K, N, Kp);
    };
    T(blk_w1, W1t0, 256, 512, 256);
    T(blk_w1 + 256 * 512, W1t1, 256, 512, 256);
    T(blk_wg, Wgt0, 256, 512, 256);
    T(blk_wg + 256 * 512, Wgt1, 256, 512, 256);
    T(blk_w2, W2t0, 512, 256, 512);
    T(blk_w2 + 512 * 256, W2t1, 512, 256, 512);
    T(rw1, RW1t, 24, 128, 32);
    T(rw2, RW2t, 128, 128, 128);
    T(agg_w1, AG1t, 256, 256, 256);
    T(agg_w2, AG2t, 256, 128, 256);

    // ---- read MLP (MFMA) -> x[:,0:128] ----
    reads_to_bf<<<(R * 32 + 255) / 256, 256, 0, stream>>>(reads, reads_bf, R);
    {
        dim3 g1((R + 63) / 64, 2);
        gemm_bf16<1><<<g1, 256, 64 * 32 * 2, stream>>>(reads_bf, RW1t, rb1, h1, nullptr,
                                                       R, 32, 3, 128, 0);
        gemm_bf16<3><<<g1, 256, 64 * 128 * 2, stream>>>(h1, RW2t, rb2, xref, xalt,
                                                        R, 128, 7, 256, TR);
    }

    // ---- variant embeddings -> x[:,128:256] ----
    variant_embed<<<V, 128, 0, stream>>>(info2d, oh, iw1, ib1, iw2, ib2, cw, cb, sw, sb, isv, V);
    long gtot = (long)R * 32;
    gather_isv<<<(int)((gtot + 255) / 256), 256, 0, stream>>>(
        (const float4*)isv, rid_r, rid_a, (float4*)xref, (float4*)xalt, TR, TA);

    // ---- 2 gated residual blocks ----
    const int ntr = (TR + 63) / 64, nta = (TA + 63) / 64;
    for (int it = 0; it < 2; ++it) {
        const unsigned short* W1t = it ? W1t1 : W1t0;
        const unsigned short* Wgt = it ? Wgt1 : Wgt0;
        const unsigned short* W2t = it ? W2t1 : W2t0;
        const float* B1 = blk_b1 + (size_t)it * 512;
        const float* Bg = blk_bg + (size_t)it * 512;
        const float* B2 = blk_b2 + (size_t)it * 256;

        seg_mean_bf<<<2 * V, 256, 0, stream>>>(xref, off_r, xalt, off_a, mref_bf, malt_bf, V);
        dim3 gg(V / 64, 8);
        // ref rows gated by alt_mean; alt rows gated by ref_mean
        gemm_bf16<2><<<gg, 256, 64 * 256 * 2, stream>>>(malt_bf, Wgt, Bg, gate_r, nullptr,
                                                        V, 256, 7, 512, 0);
        gemm_bf16<2><<<gg, 256, 64 * 256 * 2, stream>>>(mref_bf, Wgt, Bg, gate_a, nullptr,
                                                        V, 256, 7, 512, 0);
        fused_block<<<ntr + nta, 512, 0, stream>>>(xref, xalt, W1t, W2t, B1, B2,
                                                   gate_r, gate_a, rid_r, rid_a, TR, TA, ntr);
    }

    // ---- weighted alt means + agg MLP ----
    alt_wsum<<<(V + 255) / 256, 256, 0, stream>>>(au, off_a, wsum, V);
    alt_weighted_mean_bf<<<V, 256, 0, stream>>>(xalt, au, off_a, wsum, avb_bf, V);
    {
        dim3 ga(V / 64, 4);
        gemm_bf16<1><<<ga, 256, 64 * 256 * 2, stream>>>(avb_bf, AG1t, agg_b1, aggh_bf, nullptr,
                                                        V, 256, 7, 256, 0);
        dim3 go(V / 64, 2);
        gemm_bf16<0><<<go, 256, 64 * 256 * 2, stream>>>(aggh_bf, AG2t, agg_b2, d_out, nullptr,
                                                        V, 256, 7, 128, 0);
    }
}